// Round 12
// baseline (35.716 us; speedup 1.0000x reference)
//
#include <hip/hip_runtime.h>
#include <stdint.h>

// y[b,r] = sum_t x[b, idx[r,t]] * w[r,t] - bias[r]
// fp32 x (1024x4096), fp32 w (8192x32), fp32 bias (8192), int idx (8192x32), fp32 out
//
// r12: LDS-gather, 32KB slices, 512 thr, 32 waves/CU. New: each thread runs TWO
// independent r-chains (r, r+64) -> 8 independent ds_reads in flight per tg
// group (was 4), doubling per-wave LDS pipelining at fixed occupancy.

#define IN_DIM   4096
#define OUT_DIM  8192
#define BATCH    1024
#define NACT     32

#define B_SLICE      4                         // batches per LDS slice
#define N_SLICE      (BATCH / B_SLICE)         // 256
#define SLICE_WORDS  (IN_DIM * 2)              // 8192 u32 = 32 KB
#define R_PER_BLK    2048
#define N_RSPLIT     (OUT_DIM / R_PER_BLK)     // 4
#define MAIN_THREADS 512

typedef float    f2v __attribute__((ext_vector_type(2)));
typedef float    f4v __attribute__((ext_vector_type(4)));
typedef uint32_t u4v __attribute__((ext_vector_type(4)));
typedef uint32_t u2v __attribute__((ext_vector_type(2)));

__device__ __forceinline__ ushort f2bf(float f) {
    union { float f; uint32_t i; } v; v.f = f;
    uint32_t b = v.i + 0x7fffu + ((v.i >> 16) & 1u);   // RNE
    return (ushort)(b >> 16);
}
__device__ __forceinline__ float blo(uint32_t v) {
    union { uint32_t i; float f; } u; u.i = v << 16; return u.f;
}
__device__ __forceinline__ float bhi(uint32_t v) {
    union { uint32_t i; float f; } u; u.i = v & 0xffff0000u; return u.f;
}
__device__ __forceinline__ float asf(uint32_t v) {
    union { uint32_t i; float f; } u; u.i = v; return u.f;
}

// ---- idx/w -> iwPk: [rtile=r/64][tg=t/4][rl=r%64][ti=t%4] ----
// entry = (c<<3) | (bf16(w)<<16)
__global__ __launch_bounds__(256) void iw_pack(const int* __restrict__ idx,
                                               const float* __restrict__ w,
                                               uint32_t* __restrict__ iwPk) {
    __shared__ uint32_t sq[64][33];
    const int tid = threadIdx.x;
    const int r0 = blockIdx.x * 64;
    const uint32_t* gi = (const uint32_t*)idx;
    const bool idx64 = ((gi[1] | gi[3] | gi[5] | gi[7] | gi[9] | gi[11] | gi[13] | gi[15]) == 0u);
#pragma unroll
    for (int k = 0; k < 8; ++k) {
        int lin = k * 256 + tid;            // 2048 = 64 rows x 32 t
        int row = lin >> 5, t = lin & 31;
        int c;
        if (!idx64) c = idx[(size_t)(r0 + row) * NACT + t];
        else        c = idx[((size_t)(r0 + row) * NACT + t) * 2];
        float wv = w[(size_t)(r0 + row) * NACT + t];
        sq[row][t] = ((uint32_t)c << 3) | ((uint32_t)f2bf(wv) << 16);
    }
    __syncthreads();
#pragma unroll
    for (int k = 0; k < 8; ++k) {
        int lin = k * 256 + tid;            // lin = tg*256 + rl*4 + ti
        int ti = lin & 3, rl = (lin >> 2) & 63, tg = lin >> 8;
        iwPk[(size_t)blockIdx.x * 2048 + lin] = sq[rl][tg * 4 + ti];
    }
}

// ---- main: block = 4-batch slice (32 KB LDS) x 2048 rows; dual r-chains ----
__global__ __launch_bounds__(MAIN_THREADS, 8) void lds_gather4(const float* __restrict__ x,
                                                               const uint32_t* __restrict__ iwPk,
                                                               const float* __restrict__ bias,
                                                               float* __restrict__ out) {
    __shared__ uint32_t s_x[SLICE_WORDS];   // 32 KB -> 4 blocks/CU, 32 waves/CU
    const int tid = threadIdx.x;
    const int slice  = blockIdx.x >> 2;     // 256 slices
    const int rsplit = blockIdx.x & (N_RSPLIT - 1);
    const int b0  = slice * B_SLICE;
    const int r0g = rsplit * R_PER_BLK;

    { // staging: 4 fp32 rows via NT f4v; word c*2+p = batches (2p,2p+1)
        const float* xr = x + (size_t)b0 * IN_DIM;
#pragma unroll
        for (int i = 0; i < 2; ++i) {
            int c4 = (i * MAIN_THREADS + tid) * 4;
            f4v r0 = __builtin_nontemporal_load((const f4v*)(xr + c4));
            f4v r1 = __builtin_nontemporal_load((const f4v*)(xr + IN_DIM + c4));
            f4v r2 = __builtin_nontemporal_load((const f4v*)(xr + 2 * IN_DIM + c4));
            f4v r3 = __builtin_nontemporal_load((const f4v*)(xr + 3 * IN_DIM + c4));
            u4v wA, wB;
            wA.x = f2bf(r0.x) | ((uint32_t)f2bf(r1.x) << 16);
            wA.y = f2bf(r2.x) | ((uint32_t)f2bf(r3.x) << 16);
            wA.z = f2bf(r0.y) | ((uint32_t)f2bf(r1.y) << 16);
            wA.w = f2bf(r2.y) | ((uint32_t)f2bf(r3.y) << 16);
            wB.x = f2bf(r0.z) | ((uint32_t)f2bf(r1.z) << 16);
            wB.y = f2bf(r2.z) | ((uint32_t)f2bf(r3.z) << 16);
            wB.z = f2bf(r0.w) | ((uint32_t)f2bf(r1.w) << 16);
            wB.w = f2bf(r2.w) | ((uint32_t)f2bf(r3.w) << 16);
            *(u4v*)&s_x[c4 * 2]     = wA;
            *(u4v*)&s_x[c4 * 2 + 4] = wB;
        }
    }
    __syncthreads();

    const int wv = tid >> 6, lane = tid & 63;

#pragma unroll 1
    for (int pass = 0; pass < 2; ++pass) {
        // chain A: rows rA = base + wv*128 + lane; chain B: rA + 64
        const int rA = r0g + pass * 1024 + wv * 128 + lane;
        const int rB = rA + 64;
        const uint32_t* qbA = iwPk + (size_t)(rA >> 6) * 2048 + (lane << 2);
        const uint32_t* qbB = qbA + 2048;
        f2v a01A = {0.f, 0.f}, a23A = {0.f, 0.f};
        f2v a01B = {0.f, 0.f}, a23B = {0.f, 0.f};
#pragma unroll
        for (int tg = 0; tg < 8; ++tg) {
            const u4v qvA = *(const u4v*)(qbA + tg * 256);   // 4 t per dwordx4
            const u4v qvB = *(const u4v*)(qbB + tg * 256);
#pragma unroll
            for (int ti = 0; ti < 4; ++ti) {
                const uint32_t qA = qvA[ti], qB = qvB[ti];
                u2v vA = *(const u2v*)((const char*)s_x + (qA & 0x7ff8u));
                u2v vB = *(const u2v*)((const char*)s_x + (qB & 0x7ff8u));
                const float wgA = asf(qA & 0xffff0000u);
                const float wgB = asf(qB & 0xffff0000u);
                const f2v w2A = {wgA, wgA}, w2B = {wgB, wgB};
                f2v x01A = {blo(vA.x), bhi(vA.x)}, x23A = {blo(vA.y), bhi(vA.y)};
                f2v x01B = {blo(vB.x), bhi(vB.x)}, x23B = {blo(vB.y), bhi(vB.y)};
                a01A = __builtin_elementwise_fma(x01A, w2A, a01A);
                a23A = __builtin_elementwise_fma(x23A, w2A, a23A);
                a01B = __builtin_elementwise_fma(x01B, w2B, a01B);
                a23B = __builtin_elementwise_fma(x23B, w2B, a23B);
            }
        }
        const float bvA = bias[rA], bvB = bias[rB];
        const size_t obA = (size_t)b0 * OUT_DIM + rA;
        const size_t obB = (size_t)b0 * OUT_DIM + rB;
        __builtin_nontemporal_store(a01A.x - bvA, &out[obA]);
        __builtin_nontemporal_store(a01A.y - bvA, &out[obA + OUT_DIM]);
        __builtin_nontemporal_store(a23A.x - bvA, &out[obA + 2 * OUT_DIM]);
        __builtin_nontemporal_store(a23A.y - bvA, &out[obA + 3 * OUT_DIM]);
        __builtin_nontemporal_store(a01B.x - bvB, &out[obB]);
        __builtin_nontemporal_store(a01B.y - bvB, &out[obB + OUT_DIM]);
        __builtin_nontemporal_store(a23B.x - bvB, &out[obB + 2 * OUT_DIM]);
        __builtin_nontemporal_store(a23B.y - bvB, &out[obB + 3 * OUT_DIM]);
    }
}

// ---- insurance fallback (ws too small): one thread per output ----
__global__ __launch_bounds__(256) void direct_gather(const float* __restrict__ x,
                                                     const int* __restrict__ idx,
                                                     const float* __restrict__ w,
                                                     const float* __restrict__ bias,
                                                     float* __restrict__ out) {
    const uint32_t* gi = (const uint32_t*)idx;
    const bool idx64 = ((gi[1] | gi[3] | gi[5] | gi[7] | gi[9] | gi[11] | gi[13] | gi[15]) == 0u);
    int o = blockIdx.x * 256 + threadIdx.x;
    int b = o >> 13, r = o & (OUT_DIM - 1);
    float acc = 0.f;
    const float* xb = x + (size_t)b * IN_DIM;
    for (int t = 0; t < NACT; ++t) {
        int c = idx64 ? idx[((size_t)r * NACT + t) * 2] : idx[(size_t)r * NACT + t];
        acc = fmaf(xb[c], w[(size_t)r * NACT + t], acc);
    }
    out[(size_t)b * OUT_DIM + r] = acc - bias[r];
}

extern "C" void kernel_launch(void* const* d_in, const int* in_sizes, int n_in,
                              void* d_out, int out_size, void* d_ws, size_t ws_size,
                              hipStream_t stream) {
    const float* x    = (const float*)d_in[0];
    const float* wk   = (const float*)d_in[1];
    const float* bias = (const float*)d_in[2];
    const int*   idx  = (const int*)d_in[3];
    float*       out  = (float*)d_out;

    const size_t iw_bytes = (size_t)NACT * OUT_DIM * 4;   // 1 MB

    if (ws_size >= iw_bytes) {
        uint32_t* iwPk = (uint32_t*)d_ws;
        iw_pack<<<OUT_DIM / 64, 256, 0, stream>>>(idx, wk, iwPk);
        lds_gather4<<<N_SLICE * N_RSPLIT, MAIN_THREADS, 0, stream>>>(x, iwPk, bias, out);
    } else {
        direct_gather<<<(BATCH * OUT_DIM) / 256, 256, 0, stream>>>(x, idx, wk, bias, out);
    }
}